// Round 13
// baseline (64.622 us; speedup 1.0000x reference)
//
#include <hip/hip_runtime.h>

namespace {

constexpr int kBevH = 188, kBevW = 126, kP = kBevH * kBevW;   // 23688
constexpr int kB = 2, kN = 6, kC = 256, kHf = 48, kWf = 96;
constexpr int kHW = kHf * kWf;                                // 4608
constexpr int kPixBytes = kC * 2;                             // 512 B bf16
constexpr size_t kImgBytes = (size_t)kB * kN * kHW * kC * 2;  // 28.3 MB bf16
constexpr size_t kWsNeeded = kImgBytes;

// gather tiling: 32 pj x 2 pi per block; 4 pj-tiles (32,32,32,30) x 94 pi-pairs
constexpr int kPjTiles = 4, kPiGroups = kBevH / 2;            // 4, 94
constexpr int kGatherBlocks = kPjTiles * kPiGroups;           // 376 = 8*47

typedef float vfloat4 __attribute__((ext_vector_type(4)));
typedef float vfloat2 __attribute__((ext_vector_type(2)));

__device__ __forceinline__ unsigned short f2bf(float f) {     // RNE, finite
  union { float f; unsigned u; } a; a.f = f;
  unsigned r = a.u + 0x7fffu + ((a.u >> 16) & 1u);
  return (unsigned short)(r >> 16);
}
__device__ __forceinline__ float bfl(unsigned u) {
  union { unsigned u; float f; } a; a.u = u << 16; return a.f;
}
__device__ __forceinline__ float bfh(unsigned u) {
  union { unsigned u; float f; } a; a.u = u & 0xffff0000u; return a.f;
}

// ------------- K1: feats f32 [B,N,C,H,W] -> bf16 [B,N,HW,C] --------------
__global__ __launch_bounds__(256) void transpose_cvt_kernel(
    const float* __restrict__ src, unsigned short* __restrict__ dst) {
  __shared__ float tile[64][33];
  const int m = blockIdx.z;
  const int hw0 = blockIdx.x * 32;
  const int c0 = blockIdx.y * 64;
  const float* s = src + (size_t)m * kC * kHW;
  unsigned short* d = dst + (size_t)m * kHW * kC;
  const int hw = threadIdx.x & 31, cl = threadIdx.x >> 5;
#pragma unroll
  for (int k = 0; k < 8; ++k)
    tile[cl + 8 * k][hw] = s[(size_t)(c0 + cl + 8 * k) * kHW + hw0 + hw];
  __syncthreads();
  const int cp = threadIdx.x & 31, hwl = threadIdx.x >> 5;
#pragma unroll
  for (int k = 0; k < 4; ++k) {
    const int h = hwl + 8 * k;
    ushort2 uv;
    uv.x = f2bf(tile[2 * cp][h]);
    uv.y = f2bf(tile[2 * cp + 1][h]);
    *(ushort2*)(d + (size_t)(hw0 + h) * kC + c0 + 2 * cp) = uv;
  }
}

// ------------- K2: fused projection + gather, 32pj x 2pi tiles -----------
// Block = 8 waves (512 thr). j-loop orders (pj,pi0),(pj,pi1) so the
// pi-neighbor's 12 loads are L1-hot (sub-pixel shift between BEV rows).
// Epoch 0 (even row pi0): 16B-aligned float4 NT stores.
// Epoch 1 (odd row pi0+1): base ≡ 8 (mod 16) B -> use 8B-aligned float2
// NT stores (natural alignment; the float4 version was UB -> R12 bug).
__global__ __launch_bounds__(512) void gather_kernel(
    const unsigned char* __restrict__ tf, const float* __restrict__ intr,
    const float* __restrict__ c2c, float* __restrict__ out) {
  __shared__ float sm[32][261];
  __shared__ int2 s_off[64][kN];
  __shared__ float4 s_wt[64][kN];

  const int b = blockIdx.y;
  // bijective XCD swizzle: 376 = 8 * 47 exactly
  const int orig = blockIdx.x;
  const int tix = (orig & 7) * (kGatherBlocks / 8) + (orig >> 3);
  const int pjt = tix & 3;             // pj tile: 0..3 (widths 32,32,32,30)
  const int pig = tix >> 2;            // pi pair: 0..93
  const int pj0 = pjt * 32;
  const int pi0 = pig * 2;
  const int tid = threadIdx.x;

  // ---- phase 0: per-(p_local, cam) projection -> LDS records ----
  if (tid < 64 * kN) {
    const int lp = tid / kN, n = tid - lp * kN;
    const int dpi = lp >> 5, dpj = lp & 31;
    const int pj = min(pj0 + dpj, kBevW - 1);   // clamp tail dup (discarded)
    const int pi = pi0 + dpi;
    const float dxc = 75.2f / 188.0f, dyc = 50.4f / 126.0f;
    const float xcar = 0.5f * dxc + (float)pi * dxc;
    const float ycar = -25.2f + 0.5f * dyc + (float)pj * dyc;
    const float* M = c2c + ((size_t)b * kN + n) * 16;
    const float* K = intr + ((size_t)b * kN + n) * 9;
    float Xc = M[0] * xcar + M[1] * ycar + M[3];
    float Yc = M[4] * xcar + M[5] * ycar + M[7];
    float Zc = M[8] * xcar + M[9] * ycar + M[11];
    float u = K[0] * Xc + K[1] * Yc + K[2] * Zc;
    float v = K[3] * Xc + K[4] * Yc + K[5] * Zc;
    float w = K[6] * Xc + K[7] * Yc + K[8] * Zc;
    float z = fmaxf(w, 1e-4f);
    float uf = (u / z) * 0.125f;
    float vf = (v / z) * 0.125f;
    bool valid = (Zc > 0.1f) && (uf >= 0.0f) && (uf <= 95.0f) &&
                 (vf >= 0.0f) && (vf <= 47.0f);
    int2 ov = make_int2(0, 0);
    float4 wv = make_float4(0.f, 0.f, 0.f, 0.f);
    if (valid) {
      // reproduce reference op order (norm round-trip)
      float un = (uf / 95.0f) * 2.0f - 1.0f;
      float vn = (vf / 47.0f) * 2.0f - 1.0f;
      float ix = (un + 1.0f) * 0.5f * 95.0f;
      float iy = (vn + 1.0f) * 0.5f * 47.0f;
      float x0f = floorf(ix), y0f = floorf(iy);
      float wx1 = ix - x0f, wx0 = 1.0f - wx1;
      float wy1 = iy - y0f, wy0 = 1.0f - wy1;
      int x0i = (int)x0f;              // in [0,95]
      int y0i = (int)y0f;              // in [0,47]
      int xb = min(x0i, 94);           // pair base column
      float h0 = (x0i <= 94) ? wx0 : 0.0f;
      float h1 = (x0i <= 94) ? wx1 : wx0;
      int y1i = min(y0i + 1, 47);      // wy1==0 when clamped (iy==47.0)
      const int pix = (b * kN + n) * kHW;
      ov.x = (pix + y0i * kWf + xb) * kPixBytes;
      ov.y = (pix + y1i * kWf + xb) * kPixBytes;
      wv = make_float4(h0 * wy0, h1 * wy0, h0 * wy1, h1 * wy1);
    }
    s_off[lp][n] = ov;
    s_wt[lp][n] = wv;
  }
  __syncthreads();

  const int w = tid >> 6, l = tid & 63;
  const int half = l >> 5;
  const int l16 = l << 4;            // byte offset within the 1KB pair
  const int cbase = ((l & 31) << 3) + (half << 2);
  const float inv_n = 1.0f / 6.0f;

  float4 held0, held1, held2, held3;  // pi1 results (static names, no array)

#pragma unroll
  for (int j = 0; j < 8; ++j) {
    const int smrow = 4 * w + (j >> 1);
    const int lp = ((j & 1) << 5) + smrow;

    // LDS-broadcast records (uniform address per wave -> no conflicts)
    const int2 o0 = s_off[lp][0], o1 = s_off[lp][1], o2 = s_off[lp][2],
               o3 = s_off[lp][3], o4 = s_off[lp][4], o5 = s_off[lp][5];
    const float4 q0 = s_wt[lp][0], q1 = s_wt[lp][1], q2 = s_wt[lp][2],
                 q3 = s_wt[lp][3], q4 = s_wt[lp][4], q5 = s_wt[lp][5];

    // ---- issue all 12 dwordx4 loads back-to-back ----
#define LD(nm, o) \
    const uint4 nm##a = *(const uint4*)(tf + (size_t)o.x + l16); \
    const uint4 nm##b = *(const uint4*)(tf + (size_t)o.y + l16);
    LD(d0, o0) LD(d1, o1) LD(d2, o2) LD(d3, o3) LD(d4, o4) LD(d5, o5)
#undef LD

    float a0 = 0.f, a1 = 0.f, a2 = 0.f, a3 = 0.f,
          a4 = 0.f, a5 = 0.f, a6 = 0.f, a7 = 0.f;
#define CAM(da, db, wv) { \
    const float selA = half ? wv.y : wv.x; \
    const float selB = half ? wv.w : wv.z; \
    a0 += selA * bfl(da.x) + selB * bfl(db.x); \
    a1 += selA * bfh(da.x) + selB * bfh(db.x); \
    a2 += selA * bfl(da.y) + selB * bfl(db.y); \
    a3 += selA * bfh(da.y) + selB * bfh(db.y); \
    a4 += selA * bfl(da.z) + selB * bfl(db.z); \
    a5 += selA * bfh(da.z) + selB * bfh(db.z); \
    a6 += selA * bfl(da.w) + selB * bfl(db.w); \
    a7 += selA * bfh(da.w) + selB * bfh(db.w); }
    CAM(d0a, d0b, q0) CAM(d1a, d1b, q1) CAM(d2a, d2b, q2)
    CAM(d3a, d3b, q3) CAM(d4a, d4b, q4) CAM(d5a, d5b, q5)
#undef CAM

    // sum the two x-halves (lane l <-> l+32)
    a0 += __shfl_xor(a0, 32); a1 += __shfl_xor(a1, 32);
    a2 += __shfl_xor(a2, 32); a3 += __shfl_xor(a3, 32);
    a4 += __shfl_xor(a4, 32); a5 += __shfl_xor(a5, 32);
    a6 += __shfl_xor(a6, 32); a7 += __shfl_xor(a7, 32);

    float4 vs = half ? make_float4(a4, a5, a6, a7)
                     : make_float4(a0, a1, a2, a3);
    vs.x *= inv_n; vs.y *= inv_n; vs.z *= inv_n; vs.w *= inv_n;
    if ((j & 1) == 0) {
      *(float4*)&sm[smrow][cbase] = vs;      // pi0 epoch: straight to LDS
    } else {
      if ((j >> 1) == 0) held0 = vs;         // pi1 epoch: hold in regs
      else if ((j >> 1) == 1) held1 = vs;
      else if ((j >> 1) == 2) held2 = vs;
      else held3 = vs;
    }
  }
  __syncthreads();

  const int wlimit = (pjt == 3) ? 28 : 32;   // tail tile width 30

  // ---- epoch 0 write: pi0 (even) row -> 16B-aligned float4 NT stores ----
  {
    const size_t row0 = (size_t)pi0 * kBevW + pj0;
#pragma unroll
    for (int rd = 0; rd < 4; ++rd) {
      const int cr = rd * 64 + (tid >> 3);
      const int p4 = (tid & 7) * 4;
      if (p4 < wlimit) {
        vfloat4 v = {sm[p4][cr], sm[p4 + 1][cr], sm[p4 + 2][cr],
                     sm[p4 + 3][cr]};
        __builtin_nontemporal_store(
            v, (vfloat4*)(out + ((size_t)(b * kC + cr)) * kP + row0 + p4));
      }
    }
    if (pjt == 3) {  // dpj 28,29 (plain scalar stores)
      const int cr = tid >> 1, dpj = 28 + (tid & 1);
      out[((size_t)(b * kC + cr)) * kP + row0 + dpj] = sm[dpj][cr];
    }
  }
  __syncthreads();

  // ---- dump held pi1 results, then epoch 1 write (odd row) ----
  *(float4*)&sm[4 * w + 0][cbase] = held0;
  *(float4*)&sm[4 * w + 1][cbase] = held1;
  *(float4*)&sm[4 * w + 2][cbase] = held2;
  *(float4*)&sm[4 * w + 3][cbase] = held3;
  __syncthreads();
  {
    const size_t row1 = (size_t)(pi0 + 1) * kBevW + pj0;
#pragma unroll
    for (int rd = 0; rd < 4; ++rd) {
      const int cr = rd * 64 + (tid >> 3);
      const int p4 = (tid & 7) * 4;
      if (p4 < wlimit) {
        float* dst = out + ((size_t)(b * kC + cr)) * kP + row1 + p4;
        // row1 ≡ 2 (mod 4) floats -> dst is 8B-aligned: use float2 NT
        vfloat2 v01 = {sm[p4][cr], sm[p4 + 1][cr]};
        vfloat2 v23 = {sm[p4 + 2][cr], sm[p4 + 3][cr]};
        __builtin_nontemporal_store(v01, (vfloat2*)dst);
        __builtin_nontemporal_store(v23, (vfloat2*)(dst + 2));
      }
    }
    if (pjt == 3) {
      const int cr = tid >> 1, dpj = 28 + (tid & 1);
      out[((size_t)(b * kC + cr)) * kP + row1 + dpj] = sm[dpj][cr];
    }
  }
}

// ---------------- Fallback (R0 kernel) if ws too small -------------------
constexpr int kCChunk = 32;
__global__ __launch_bounds__(256) void ipm_project_kernel(
    const float* __restrict__ feats, const float* __restrict__ intr,
    const float* __restrict__ c2c, float* __restrict__ out) {
  const int p = blockIdx.x * 256 + threadIdx.x;
  const int b = blockIdx.y;
  const int c0 = blockIdx.z * kCChunk;
  const bool inrange = p < kP;
  const int pi = p / kBevW;
  const int pj = p - pi * kBevW;
  const float dx = 75.2f / 188.0f;
  const float dy = 50.4f / 126.0f;
  const float xcar = 0.5f * dx + (float)pi * dx;
  const float ycar = -25.2f + 0.5f * dy + (float)pj * dy;
  int tap[kN][4];
  float tw[kN][4];
  int vmask = 0;
  const float* Kb = intr + (size_t)b * kN * 9;
  const float* Mb = c2c + (size_t)b * kN * 16;
#pragma unroll
  for (int n = 0; n < kN; ++n) {
    const float* M = Mb + n * 16;
    const float* K = Kb + n * 9;
    float Xc = M[0] * xcar + M[1] * ycar + M[3];
    float Yc = M[4] * xcar + M[5] * ycar + M[7];
    float Zc = M[8] * xcar + M[9] * ycar + M[11];
    float u = K[0] * Xc + K[1] * Yc + K[2] * Zc;
    float v = K[3] * Xc + K[4] * Yc + K[5] * Zc;
    float w = K[6] * Xc + K[7] * Yc + K[8] * Zc;
    float z = fmaxf(w, 1e-4f);
    float uf = (u / z) * 0.125f;
    float vf = (v / z) * 0.125f;
    bool valid = inrange && (Zc > 0.1f) && (uf >= 0.0f) && (uf <= 95.0f) &&
                 (vf >= 0.0f) && (vf <= 47.0f);
    if (valid) {
      float un = (uf / 95.0f) * 2.0f - 1.0f;
      float vn = (vf / 47.0f) * 2.0f - 1.0f;
      float ix = (un + 1.0f) * 0.5f * 95.0f;
      float iy = (vn + 1.0f) * 0.5f * 47.0f;
      float x0f = floorf(ix), y0f = floorf(iy);
      float wx1 = ix - x0f, wx0 = 1.0f - wx1;
      float wy1 = iy - y0f, wy0 = 1.0f - wy1;
#pragma unroll
      for (int t = 0; t < 4; ++t) {
        float xf = x0f + (float)(t & 1);
        float yf = y0f + (float)(t >> 1);
        bool inb =
            (xf >= 0.0f) && (xf <= 95.0f) && (yf >= 0.0f) && (yf <= 47.0f);
        int xi = (int)fminf(fmaxf(xf, 0.0f), 95.0f);
        int yi = (int)fminf(fmaxf(yf, 0.0f), 47.0f);
        float wgt = ((t & 1) ? wx1 : wx0) * ((t >> 1) ? wy1 : wy0);
        tap[n][t] = yi * kWf + xi;
        tw[n][t] = inb ? wgt : 0.0f;
      }
      vmask |= (1 << n);
    }
  }
  const float inv_n = 1.0f / 6.0f;
#pragma unroll 4
  for (int k = 0; k < kCChunk; ++k) {
    const int c = c0 + k;
    float acc = 0.0f;
#pragma unroll
    for (int n = 0; n < kN; ++n) {
      if (vmask & (1 << n)) {
        const float* f = feats + ((size_t)(b * kN + n) * kC + c) * kHW;
        acc += f[tap[n][0]] * tw[n][0] + f[tap[n][1]] * tw[n][1] +
               f[tap[n][2]] * tw[n][2] + f[tap[n][3]] * tw[n][3];
      }
    }
    if (inrange) out[((size_t)b * kC + c) * kP + p] = acc * inv_n;
  }
}

}  // namespace

extern "C" void kernel_launch(void* const* d_in, const int* in_sizes, int n_in,
                              void* d_out, int out_size, void* d_ws,
                              size_t ws_size, hipStream_t stream) {
  const float* feats = (const float*)d_in[0];
  const float* intr = (const float*)d_in[1];
  const float* c2c = (const float*)d_in[2];
  float* out = (float*)d_out;

  if (ws_size >= kWsNeeded && d_ws != nullptr) {
    unsigned short* tf = (unsigned short*)d_ws;
    transpose_cvt_kernel<<<dim3(kHW / 32, kC / 64, kB * kN), 256, 0, stream>>>(
        feats, tf);
    gather_kernel<<<dim3(kGatherBlocks, kB), 512, 0, stream>>>(
        (const unsigned char*)tf, intr, c2c, out);
  } else {
    dim3 grid((kP + 255) / 256, kB, kC / kCChunk);
    ipm_project_kernel<<<grid, dim3(256), 0, stream>>>(feats, intr, c2c, out);
  }
}

// Round 14
// 54.622 us; speedup vs baseline: 1.1831x; 1.1831x over previous
//
#include <hip/hip_runtime.h>

namespace {

constexpr int kBevH = 188, kBevW = 126, kP = kBevH * kBevW;   // 23688
constexpr int kB = 2, kN = 6, kC = 256, kHf = 48, kWf = 96;
constexpr int kHW = kHf * kWf;                                // 4608
constexpr int kPixBytes = kC * 2;                             // 512 B bf16
constexpr size_t kImgBytes = (size_t)kB * kN * kHW * kC * 2;  // 28.3 MB bf16
constexpr size_t kWsNeeded = kImgBytes;

// gather tiling: 16 pj x 2 pi per block; 8 pj-strips (16x7 + tail 14) x 94
constexpr int kPjTiles = 8, kPiGroups = kBevH / 2;            // 8, 94
constexpr int kGatherBlocks = kPjTiles * kPiGroups;           // 752 = 8*94

typedef float vfloat4 __attribute__((ext_vector_type(4)));
typedef float vfloat2 __attribute__((ext_vector_type(2)));

__device__ __forceinline__ unsigned short f2bf(float f) {     // RNE, finite
  union { float f; unsigned u; } a; a.f = f;
  unsigned r = a.u + 0x7fffu + ((a.u >> 16) & 1u);
  return (unsigned short)(r >> 16);
}
__device__ __forceinline__ float bfl(unsigned u) {
  union { unsigned u; float f; } a; a.u = u << 16; return a.f;
}
__device__ __forceinline__ float bfh(unsigned u) {
  union { unsigned u; float f; } a; a.u = u & 0xffff0000u; return a.f;
}

// ------------- K1: feats f32 [B,N,C,H,W] -> bf16 [B,N,HW,C] --------------
__global__ __launch_bounds__(256) void transpose_cvt_kernel(
    const float* __restrict__ src, unsigned short* __restrict__ dst) {
  __shared__ float tile[64][33];
  const int m = blockIdx.z;
  const int hw0 = blockIdx.x * 32;
  const int c0 = blockIdx.y * 64;
  const float* s = src + (size_t)m * kC * kHW;
  unsigned short* d = dst + (size_t)m * kHW * kC;
  const int hw = threadIdx.x & 31, cl = threadIdx.x >> 5;
#pragma unroll
  for (int k = 0; k < 8; ++k)
    tile[cl + 8 * k][hw] = s[(size_t)(c0 + cl + 8 * k) * kHW + hw0 + hw];
  __syncthreads();
  const int cp = threadIdx.x & 31, hwl = threadIdx.x >> 5;
#pragma unroll
  for (int k = 0; k < 4; ++k) {
    const int h = hwl + 8 * k;
    ushort2 uv;
    uv.x = f2bf(tile[2 * cp][h]);
    uv.y = f2bf(tile[2 * cp + 1][h]);
    *(ushort2*)(d + (size_t)(hw0 + h) * kC + c0 + 2 * cp) = uv;
  }
}

// ------------- K2: fused projection + gather, 16pj x 2pi tiles -----------
// Block = 8 waves (512 thr), 32 p (16 pj x 2 pi), all 256 c.
// Wave w owns pj in {2w, 2w+1} x pi in {0,1}; j-order (pj,pi0),(pj,pi1)
// so the pi-neighbor's 12 loads are L1-hot (sub-pixel shift between BEV
// depth rows). Both rows fit sm[32] -> NO held regs (VGPR low), single
// write phase. pjt = blockIdx.x & 7: each XCD owns one pj-strip and
// sweeps pi -> L2-local. Even row: NT float4; odd row: PLAIN float2
// (plain stores let L2 write-combine; NT partials caused R13's +19MB).
__global__ __launch_bounds__(512) void gather_kernel(
    const unsigned char* __restrict__ tf, const float* __restrict__ intr,
    const float* __restrict__ c2c, float* __restrict__ out) {
  __shared__ float sm[32][261];       // rows 0-15: pi0, rows 16-31: pi1
  __shared__ int2 s_off[32][kN];
  __shared__ float4 s_wt[32][kN];

  const int b = blockIdx.y;
  const int orig = blockIdx.x;        // 752 = 8 * 94
  const int pjt = orig & 7;           // pj strip (width 16; strip 7 -> 14)
  const int pig = orig >> 3;          // pi pair: 0..93
  const int pj0 = pjt * 16;
  const int pi0 = pig * 2;
  const int tid = threadIdx.x;

  // ---- phase 0: per-(p_local, cam) projection -> LDS records ----
  if (tid < 32 * kN) {
    const int lp = tid / kN, n = tid - lp * kN;   // lp = dpi*16 + dpj
    const int dpi = lp >> 4, dpj = lp & 15;
    const int pj = min(pj0 + dpj, kBevW - 1);     // tail dup (discarded)
    const int pi = pi0 + dpi;
    const float dxc = 75.2f / 188.0f, dyc = 50.4f / 126.0f;
    const float xcar = 0.5f * dxc + (float)pi * dxc;
    const float ycar = -25.2f + 0.5f * dyc + (float)pj * dyc;
    const float* M = c2c + ((size_t)b * kN + n) * 16;
    const float* K = intr + ((size_t)b * kN + n) * 9;
    float Xc = M[0] * xcar + M[1] * ycar + M[3];
    float Yc = M[4] * xcar + M[5] * ycar + M[7];
    float Zc = M[8] * xcar + M[9] * ycar + M[11];
    float u = K[0] * Xc + K[1] * Yc + K[2] * Zc;
    float v = K[3] * Xc + K[4] * Yc + K[5] * Zc;
    float w = K[6] * Xc + K[7] * Yc + K[8] * Zc;
    float z = fmaxf(w, 1e-4f);
    float uf = (u / z) * 0.125f;
    float vf = (v / z) * 0.125f;
    bool valid = (Zc > 0.1f) && (uf >= 0.0f) && (uf <= 95.0f) &&
                 (vf >= 0.0f) && (vf <= 47.0f);
    int2 ov = make_int2(0, 0);
    float4 wv = make_float4(0.f, 0.f, 0.f, 0.f);
    if (valid) {
      // reproduce reference op order (norm round-trip)
      float un = (uf / 95.0f) * 2.0f - 1.0f;
      float vn = (vf / 47.0f) * 2.0f - 1.0f;
      float ix = (un + 1.0f) * 0.5f * 95.0f;
      float iy = (vn + 1.0f) * 0.5f * 47.0f;
      float x0f = floorf(ix), y0f = floorf(iy);
      float wx1 = ix - x0f, wx0 = 1.0f - wx1;
      float wy1 = iy - y0f, wy0 = 1.0f - wy1;
      int x0i = (int)x0f;              // in [0,95]
      int y0i = (int)y0f;              // in [0,47]
      int xb = min(x0i, 94);           // pair base column
      float h0 = (x0i <= 94) ? wx0 : 0.0f;
      float h1 = (x0i <= 94) ? wx1 : wx0;
      int y1i = min(y0i + 1, 47);      // wy1==0 when clamped (iy==47.0)
      const int pix = (b * kN + n) * kHW;
      ov.x = (pix + y0i * kWf + xb) * kPixBytes;
      ov.y = (pix + y1i * kWf + xb) * kPixBytes;
      wv = make_float4(h0 * wy0, h1 * wy0, h0 * wy1, h1 * wy1);
    }
    s_off[lp][n] = ov;
    s_wt[lp][n] = wv;
  }
  __syncthreads();

  const int w = tid >> 6, l = tid & 63;
  const int half = l >> 5;
  const int l16 = l << 4;            // byte offset within the 1KB pair
  const int cbase = ((l & 31) << 3) + (half << 2);
  const float inv_n = 1.0f / 6.0f;

#pragma unroll
  for (int j = 0; j < 4; ++j) {
    const int dpj = 2 * w + (j >> 1);
    const int dpi = j & 1;
    const int lp = dpi * 16 + dpj;     // record row AND sm row

    // LDS-broadcast records (uniform address per wave -> no conflicts)
    const int2 o0 = s_off[lp][0], o1 = s_off[lp][1], o2 = s_off[lp][2],
               o3 = s_off[lp][3], o4 = s_off[lp][4], o5 = s_off[lp][5];
    const float4 q0 = s_wt[lp][0], q1 = s_wt[lp][1], q2 = s_wt[lp][2],
                 q3 = s_wt[lp][3], q4 = s_wt[lp][4], q5 = s_wt[lp][5];

    // ---- issue all 12 dwordx4 loads back-to-back ----
#define LD(nm, o) \
    const uint4 nm##a = *(const uint4*)(tf + (size_t)o.x + l16); \
    const uint4 nm##b = *(const uint4*)(tf + (size_t)o.y + l16);
    LD(d0, o0) LD(d1, o1) LD(d2, o2) LD(d3, o3) LD(d4, o4) LD(d5, o5)
#undef LD

    float a0 = 0.f, a1 = 0.f, a2 = 0.f, a3 = 0.f,
          a4 = 0.f, a5 = 0.f, a6 = 0.f, a7 = 0.f;
#define CAM(da, db, wv) { \
    const float selA = half ? wv.y : wv.x; \
    const float selB = half ? wv.w : wv.z; \
    a0 += selA * bfl(da.x) + selB * bfl(db.x); \
    a1 += selA * bfh(da.x) + selB * bfh(db.x); \
    a2 += selA * bfl(da.y) + selB * bfl(db.y); \
    a3 += selA * bfh(da.y) + selB * bfh(db.y); \
    a4 += selA * bfl(da.z) + selB * bfl(db.z); \
    a5 += selA * bfh(da.z) + selB * bfh(db.z); \
    a6 += selA * bfl(da.w) + selB * bfl(db.w); \
    a7 += selA * bfh(da.w) + selB * bfh(db.w); }
    CAM(d0a, d0b, q0) CAM(d1a, d1b, q1) CAM(d2a, d2b, q2)
    CAM(d3a, d3b, q3) CAM(d4a, d4b, q4) CAM(d5a, d5b, q5)
#undef CAM

    // sum the two x-halves (lane l <-> l+32)
    a0 += __shfl_xor(a0, 32); a1 += __shfl_xor(a1, 32);
    a2 += __shfl_xor(a2, 32); a3 += __shfl_xor(a3, 32);
    a4 += __shfl_xor(a4, 32); a5 += __shfl_xor(a5, 32);
    a6 += __shfl_xor(a6, 32); a7 += __shfl_xor(a7, 32);

    float4 vs = half ? make_float4(a4, a5, a6, a7)
                     : make_float4(a0, a1, a2, a3);
    vs.x *= inv_n; vs.y *= inv_n; vs.z *= inv_n; vs.w *= inv_n;
    *(float4*)&sm[lp][cbase] = vs;
  }
  __syncthreads();

  const int wlimit = (pjt == 7) ? 14 : 16;
  const int nfull = wlimit & ~3;               // 12 or 16

  // ---- row0 (even pi): 16B-aligned NT float4 stores ----
  {
    const size_t row0 = (size_t)pi0 * kBevW + pj0;   // ≡ 0 mod 4
#pragma unroll
    for (int rd = 0; rd < 2; ++rd) {
      const int cr = rd * 128 + (tid >> 2);
      const int p4 = (tid & 3) * 4;
      if (p4 < nfull) {
        vfloat4 v = {sm[p4][cr], sm[p4 + 1][cr], sm[p4 + 2][cr],
                     sm[p4 + 3][cr]};
        __builtin_nontemporal_store(
            v, (vfloat4*)(out + ((size_t)(b * kC + cr)) * kP + row0 + p4));
      }
    }
    if (pjt == 7) {  // tail cols 12,13 (plain scalar)
      const int cr = tid >> 1, dpj = 12 + (tid & 1);
      out[((size_t)(b * kC + cr)) * kP + row0 + dpj] = sm[dpj][cr];
    }
  }

  // ---- row1 (odd pi): 8B-aligned PLAIN float2 stores ----
  {
    const size_t row1 = (size_t)(pi0 + 1) * kBevW + pj0;   // ≡ 2 mod 4
#pragma unroll
    for (int rd = 0; rd < 4; ++rd) {
      const int cr = rd * 64 + (tid >> 3);
      const int p2 = (tid & 7) * 2;
      if (p2 + 2 <= wlimit) {
        vfloat2 v = {sm[16 + p2][cr], sm[16 + p2 + 1][cr]};
        *(vfloat2*)(out + ((size_t)(b * kC + cr)) * kP + row1 + p2) = v;
      }
    }
  }
}

// ---------------- Fallback (R0 kernel) if ws too small -------------------
constexpr int kCChunk = 32;
__global__ __launch_bounds__(256) void ipm_project_kernel(
    const float* __restrict__ feats, const float* __restrict__ intr,
    const float* __restrict__ c2c, float* __restrict__ out) {
  const int p = blockIdx.x * 256 + threadIdx.x;
  const int b = blockIdx.y;
  const int c0 = blockIdx.z * kCChunk;
  const bool inrange = p < kP;
  const int pi = p / kBevW;
  const int pj = p - pi * kBevW;
  const float dx = 75.2f / 188.0f;
  const float dy = 50.4f / 126.0f;
  const float xcar = 0.5f * dx + (float)pi * dx;
  const float ycar = -25.2f + 0.5f * dy + (float)pj * dy;
  int tap[kN][4];
  float tw[kN][4];
  int vmask = 0;
  const float* Kb = intr + (size_t)b * kN * 9;
  const float* Mb = c2c + (size_t)b * kN * 16;
#pragma unroll
  for (int n = 0; n < kN; ++n) {
    const float* M = Mb + n * 16;
    const float* K = Kb + n * 9;
    float Xc = M[0] * xcar + M[1] * ycar + M[3];
    float Yc = M[4] * xcar + M[5] * ycar + M[7];
    float Zc = M[8] * xcar + M[9] * ycar + M[11];
    float u = K[0] * Xc + K[1] * Yc + K[2] * Zc;
    float v = K[3] * Xc + K[4] * Yc + K[5] * Zc;
    float w = K[6] * Xc + K[7] * Yc + K[8] * Zc;
    float z = fmaxf(w, 1e-4f);
    float uf = (u / z) * 0.125f;
    float vf = (v / z) * 0.125f;
    bool valid = inrange && (Zc > 0.1f) && (uf >= 0.0f) && (uf <= 95.0f) &&
                 (vf >= 0.0f) && (vf <= 47.0f);
    if (valid) {
      float un = (uf / 95.0f) * 2.0f - 1.0f;
      float vn = (vf / 47.0f) * 2.0f - 1.0f;
      float ix = (un + 1.0f) * 0.5f * 95.0f;
      float iy = (vn + 1.0f) * 0.5f * 47.0f;
      float x0f = floorf(ix), y0f = floorf(iy);
      float wx1 = ix - x0f, wx0 = 1.0f - wx1;
      float wy1 = iy - y0f, wy0 = 1.0f - wy1;
#pragma unroll
      for (int t = 0; t < 4; ++t) {
        float xf = x0f + (float)(t & 1);
        float yf = y0f + (float)(t >> 1);
        bool inb =
            (xf >= 0.0f) && (xf <= 95.0f) && (yf >= 0.0f) && (yf <= 47.0f);
        int xi = (int)fminf(fmaxf(xf, 0.0f), 95.0f);
        int yi = (int)fminf(fmaxf(yf, 0.0f), 47.0f);
        float wgt = ((t & 1) ? wx1 : wx0) * ((t >> 1) ? wy1 : wy0);
        tap[n][t] = yi * kWf + xi;
        tw[n][t] = inb ? wgt : 0.0f;
      }
      vmask |= (1 << n);
    }
  }
  const float inv_n = 1.0f / 6.0f;
#pragma unroll 4
  for (int k = 0; k < kCChunk; ++k) {
    const int c = c0 + k;
    float acc = 0.0f;
#pragma unroll
    for (int n = 0; n < kN; ++n) {
      if (vmask & (1 << n)) {
        const float* f = feats + ((size_t)(b * kN + n) * kC + c) * kHW;
        acc += f[tap[n][0]] * tw[n][0] + f[tap[n][1]] * tw[n][1] +
               f[tap[n][2]] * tw[n][2] + f[tap[n][3]] * tw[n][3];
      }
    }
    if (inrange) out[((size_t)b * kC + c) * kP + p] = acc * inv_n;
  }
}

}  // namespace

extern "C" void kernel_launch(void* const* d_in, const int* in_sizes, int n_in,
                              void* d_out, int out_size, void* d_ws,
                              size_t ws_size, hipStream_t stream) {
  const float* feats = (const float*)d_in[0];
  const float* intr = (const float*)d_in[1];
  const float* c2c = (const float*)d_in[2];
  float* out = (float*)d_out;

  if (ws_size >= kWsNeeded && d_ws != nullptr) {
    unsigned short* tf = (unsigned short*)d_ws;
    transpose_cvt_kernel<<<dim3(kHW / 32, kC / 64, kB * kN), 256, 0, stream>>>(
        feats, tf);
    gather_kernel<<<dim3(kGatherBlocks, kB), 512, 0, stream>>>(
        (const unsigned char*)tf, intr, c2c, out);
  } else {
    dim3 grid((kP + 255) / 256, kB, kC / kCChunk);
    ipm_project_kernel<<<grid, dim3(256), 0, stream>>>(feats, intr, c2c, out);
  }
}

// Round 15
// 46.722 us; speedup vs baseline: 1.3831x; 1.1691x over previous
//
#include <hip/hip_runtime.h>

namespace {

constexpr int kBevH = 188, kBevW = 126, kP = kBevH * kBevW;   // 23688
constexpr int kB = 2, kN = 6, kC = 256, kHf = 48, kWf = 96;
constexpr int kHW = kHf * kWf;                                // 4608
constexpr int kPixBytes = kC * 2;                             // 512 B bf16
constexpr int kPTile = 32;
constexpr int kNTiles = (kP + kPTile - 1) / kPTile;           // 741
constexpr size_t kImgBytes = (size_t)kB * kN * kHW * kC * 2;  // 28.3 MB bf16
constexpr size_t kWsNeeded = kImgBytes;

typedef float vfloat4 __attribute__((ext_vector_type(4)));
typedef float vfloat2 __attribute__((ext_vector_type(2)));

__device__ __forceinline__ unsigned short f2bf(float f) {     // RNE, finite
  union { float f; unsigned u; } a; a.f = f;
  unsigned r = a.u + 0x7fffu + ((a.u >> 16) & 1u);
  return (unsigned short)(r >> 16);
}
__device__ __forceinline__ float bfl(unsigned u) {
  union { unsigned u; float f; } a; a.u = u << 16; return a.f;
}
__device__ __forceinline__ float bfh(unsigned u) {
  union { unsigned u; float f; } a; a.u = u & 0xffff0000u; return a.f;
}

// ------------- K1: feats f32 [B,N,C,H,W] -> bf16 [B,N,HW,C] --------------
__global__ __launch_bounds__(256) void transpose_cvt_kernel(
    const float* __restrict__ src, unsigned short* __restrict__ dst) {
  __shared__ float tile[64][33];
  const int m = blockIdx.z;
  const int hw0 = blockIdx.x * 32;
  const int c0 = blockIdx.y * 64;
  const float* s = src + (size_t)m * kC * kHW;
  unsigned short* d = dst + (size_t)m * kHW * kC;
  const int hw = threadIdx.x & 31, cl = threadIdx.x >> 5;
#pragma unroll
  for (int k = 0; k < 8; ++k)
    tile[cl + 8 * k][hw] = s[(size_t)(c0 + cl + 8 * k) * kHW + hw0 + hw];
  __syncthreads();
  const int cp = threadIdx.x & 31, hwl = threadIdx.x >> 5;
#pragma unroll
  for (int k = 0; k < 4; ++k) {
    const int h = hwl + 8 * k;
    ushort2 uv;
    uv.x = f2bf(tile[2 * cp][h]);
    uv.y = f2bf(tile[2 * cp + 1][h]);
    *(ushort2*)(d + (size_t)(hw0 + h) * kC + c0 + 2 * cp) = uv;
  }
}

// ------------- K2: fused projection + paired-dwordx4 gather --------------
// R11 macro-structure (proven fastest): 32 consecutive p per block, m204
// chunked XCD swizzle (adjacent tiles same XCD -> full-line L2 writes).
// VALU diet: float2 packed math (v_pk_fma_f32), per-half weights in LDS
// (no cndmask), 1/6 folded into weights.
__global__ __launch_bounds__(512) void gather_kernel(
    const unsigned char* __restrict__ tf, const float* __restrict__ intr,
    const float* __restrict__ c2c, float* __restrict__ out) {
  __shared__ float sm[kPTile][261];
  __shared__ int2 s_off[kPTile][kN];
  __shared__ vfloat2 s_wt2[kPTile][kN][2];   // [half] = {w_y0row, w_y1row}/6

  const int b = blockIdx.y;
  // bijective XCD swizzle (m204): contiguous tile chunk per XCD
  const int orig = blockIdx.x;
  constexpr int q = kNTiles / 8, r = kNTiles % 8;  // 92, 5
  const int xcd = orig & 7, idx = orig >> 3;
  const int tile = (xcd < r ? xcd * (q + 1) : r * (q + 1) + (xcd - r) * q) + idx;
  const int p0 = tile * kPTile;
  const int tid = threadIdx.x;

  // ---- phase 0: per-(p_local, cam) projection -> LDS records ----
  if (tid < kPTile * kN) {
    const int pl = tid / kN, n = tid - pl * kN;
    const int p = min(p0 + pl, kP - 1);
    const int pi = p / kBevW, pj = p - pi * kBevW;
    const float dxc = 75.2f / 188.0f, dyc = 50.4f / 126.0f;
    const float xcar = 0.5f * dxc + (float)pi * dxc;
    const float ycar = -25.2f + 0.5f * dyc + (float)pj * dyc;
    const float* M = c2c + ((size_t)b * kN + n) * 16;
    const float* K = intr + ((size_t)b * kN + n) * 9;
    float Xc = M[0] * xcar + M[1] * ycar + M[3];
    float Yc = M[4] * xcar + M[5] * ycar + M[7];
    float Zc = M[8] * xcar + M[9] * ycar + M[11];
    float u = K[0] * Xc + K[1] * Yc + K[2] * Zc;
    float v = K[3] * Xc + K[4] * Yc + K[5] * Zc;
    float w = K[6] * Xc + K[7] * Yc + K[8] * Zc;
    float z = fmaxf(w, 1e-4f);
    float uf = (u / z) * 0.125f;
    float vf = (v / z) * 0.125f;
    bool valid = (Zc > 0.1f) && (uf >= 0.0f) && (uf <= 95.0f) &&
                 (vf >= 0.0f) && (vf <= 47.0f);
    int2 ov = make_int2(0, 0);
    vfloat2 w0 = {0.f, 0.f}, w1 = {0.f, 0.f};
    if (valid) {
      // reproduce reference op order (norm round-trip)
      float un = (uf / 95.0f) * 2.0f - 1.0f;
      float vn = (vf / 47.0f) * 2.0f - 1.0f;
      float ix = (un + 1.0f) * 0.5f * 95.0f;
      float iy = (vn + 1.0f) * 0.5f * 47.0f;
      float x0f = floorf(ix), y0f = floorf(iy);
      float wx1 = ix - x0f, wx0 = 1.0f - wx1;
      float wy1 = iy - y0f, wy0 = 1.0f - wy1;
      int x0i = (int)x0f;              // in [0,95]
      int y0i = (int)y0f;              // in [0,47]
      int xb = min(x0i, 94);           // pair base column
      float h0 = (x0i <= 94) ? wx0 : 0.0f;
      float h1 = (x0i <= 94) ? wx1 : wx0;
      int y1i = min(y0i + 1, 47);      // wy1==0 when clamped (iy==47.0)
      const int pix = (b * kN + n) * kHW;
      ov.x = (pix + y0i * kWf + xb) * kPixBytes;
      ov.y = (pix + y1i * kWf + xb) * kPixBytes;
      const float s6 = 1.0f / 6.0f;    // fold mean over cams into weights
      w0 = (vfloat2){h0 * wy0 * s6, h0 * wy1 * s6};   // half 0 (x0 tap)
      w1 = (vfloat2){h1 * wy0 * s6, h1 * wy1 * s6};   // half 1 (x1 tap)
    }
    s_off[pl][n] = ov;
    s_wt2[pl][n][0] = w0;
    s_wt2[pl][n][1] = w1;
  }
  __syncthreads();

  const int w = tid >> 6, l = tid & 63;
  const int half = l >> 5;
  const int l16 = l << 4;            // byte offset within the 1KB pair
  const int cbase = ((l & 31) << 3) + (half << 2);

#pragma unroll
  for (int j = 0; j < 4; ++j) {
    const int pl = w * 4 + j;

    // LDS-broadcast records (<=2 unique addrs per wave -> free broadcast)
    const int2 o0 = s_off[pl][0], o1 = s_off[pl][1], o2 = s_off[pl][2],
               o3 = s_off[pl][3], o4 = s_off[pl][4], o5 = s_off[pl][5];
    const vfloat2 q0 = s_wt2[pl][0][half], q1 = s_wt2[pl][1][half],
                  q2 = s_wt2[pl][2][half], q3 = s_wt2[pl][3][half],
                  q4 = s_wt2[pl][4][half], q5 = s_wt2[pl][5][half];

    // ---- issue all 12 dwordx4 loads back-to-back ----
#define LD(nm, o) \
    const uint4 nm##a = *(const uint4*)(tf + (size_t)o.x + l16); \
    const uint4 nm##b = *(const uint4*)(tf + (size_t)o.y + l16);
    LD(d0, o0) LD(d1, o1) LD(d2, o2) LD(d3, o3) LD(d4, o4) LD(d5, o5)
#undef LD

    vfloat2 ac0 = {0.f, 0.f}, ac1 = {0.f, 0.f},
            ac2 = {0.f, 0.f}, ac3 = {0.f, 0.f};
    // packed math: wv.x (y0-row weight) * da + wv.y (y1-row weight) * db,
    // two channels per v_pk_fma_f32
#define CAM(da, db, wv) { \
    const vfloat2 wA = {wv.x, wv.x}; \
    const vfloat2 wB = {wv.y, wv.y}; \
    ac0 += wA * (vfloat2){bfl(da.x), bfh(da.x)} \
         + wB * (vfloat2){bfl(db.x), bfh(db.x)}; \
    ac1 += wA * (vfloat2){bfl(da.y), bfh(da.y)} \
         + wB * (vfloat2){bfl(db.y), bfh(db.y)}; \
    ac2 += wA * (vfloat2){bfl(da.z), bfh(da.z)} \
         + wB * (vfloat2){bfl(db.z), bfh(db.z)}; \
    ac3 += wA * (vfloat2){bfl(da.w), bfh(da.w)} \
         + wB * (vfloat2){bfl(db.w), bfh(db.w)}; }
    CAM(d0a, d0b, q0) CAM(d1a, d1b, q1) CAM(d2a, d2b, q2)
    CAM(d3a, d3b, q3) CAM(d4a, d4b, q4) CAM(d5a, d5b, q5)
#undef CAM

    // sum the two x-halves (lane l <-> l+32)
    ac0.x += __shfl_xor(ac0.x, 32); ac0.y += __shfl_xor(ac0.y, 32);
    ac1.x += __shfl_xor(ac1.x, 32); ac1.y += __shfl_xor(ac1.y, 32);
    ac2.x += __shfl_xor(ac2.x, 32); ac2.y += __shfl_xor(ac2.y, 32);
    ac3.x += __shfl_xor(ac3.x, 32); ac3.y += __shfl_xor(ac3.y, 32);

    // lane handles channels 8*(l&31)..+7; half0 stores ch+0..3, half1 +4..7
    vfloat4 vs = half ? (vfloat4){ac2.x, ac2.y, ac3.x, ac3.y}
                      : (vfloat4){ac0.x, ac0.y, ac1.x, ac1.y};
    *(vfloat4*)&sm[pl][cbase] = vs;
  }
  __syncthreads();

  // write: 4 rounds; each round = 64 c-rows x 32 consecutive p (coalesced)
#pragma unroll
  for (int rd = 0; rd < 4; ++rd) {
    const int cr = rd * 64 + (tid >> 3);
    const int p4 = (tid & 7) * 4;
    const int pg = p0 + p4;
    if (pg < kP) {  // kP%4==0 -> whole float4 chunk valid
      vfloat4 v = {sm[p4][cr], sm[p4 + 1][cr], sm[p4 + 2][cr],
                   sm[p4 + 3][cr]};
      __builtin_nontemporal_store(
          v, (vfloat4*)(out + ((size_t)(b * kC + cr)) * kP + pg));
    }
  }
}

// ---------------- Fallback (R0 kernel) if ws too small -------------------
constexpr int kCChunk = 32;
__global__ __launch_bounds__(256) void ipm_project_kernel(
    const float* __restrict__ feats, const float* __restrict__ intr,
    const float* __restrict__ c2c, float* __restrict__ out) {
  const int p = blockIdx.x * 256 + threadIdx.x;
  const int b = blockIdx.y;
  const int c0 = blockIdx.z * kCChunk;
  const bool inrange = p < kP;
  const int pi = p / kBevW;
  const int pj = p - pi * kBevW;
  const float dx = 75.2f / 188.0f;
  const float dy = 50.4f / 126.0f;
  const float xcar = 0.5f * dx + (float)pi * dx;
  const float ycar = -25.2f + 0.5f * dy + (float)pj * dy;
  int tap[kN][4];
  float tw[kN][4];
  int vmask = 0;
  const float* Kb = intr + (size_t)b * kN * 9;
  const float* Mb = c2c + (size_t)b * kN * 16;
#pragma unroll
  for (int n = 0; n < kN; ++n) {
    const float* M = Mb + n * 16;
    const float* K = Kb + n * 9;
    float Xc = M[0] * xcar + M[1] * ycar + M[3];
    float Yc = M[4] * xcar + M[5] * ycar + M[7];
    float Zc = M[8] * xcar + M[9] * ycar + M[11];
    float u = K[0] * Xc + K[1] * Yc + K[2] * Zc;
    float v = K[3] * Xc + K[4] * Yc + K[5] * Zc;
    float w = K[6] * Xc + K[7] * Yc + K[8] * Zc;
    float z = fmaxf(w, 1e-4f);
    float uf = (u / z) * 0.125f;
    float vf = (v / z) * 0.125f;
    bool valid = inrange && (Zc > 0.1f) && (uf >= 0.0f) && (uf <= 95.0f) &&
                 (vf >= 0.0f) && (vf <= 47.0f);
    if (valid) {
      float un = (uf / 95.0f) * 2.0f - 1.0f;
      float vn = (vf / 47.0f) * 2.0f - 1.0f;
      float ix = (un + 1.0f) * 0.5f * 95.0f;
      float iy = (vn + 1.0f) * 0.5f * 47.0f;
      float x0f = floorf(ix), y0f = floorf(iy);
      float wx1 = ix - x0f, wx0 = 1.0f - wx1;
      float wy1 = iy - y0f, wy0 = 1.0f - wy1;
#pragma unroll
      for (int t = 0; t < 4; ++t) {
        float xf = x0f + (float)(t & 1);
        float yf = y0f + (float)(t >> 1);
        bool inb =
            (xf >= 0.0f) && (xf <= 95.0f) && (yf >= 0.0f) && (yf <= 47.0f);
        int xi = (int)fminf(fmaxf(xf, 0.0f), 95.0f);
        int yi = (int)fminf(fmaxf(yf, 0.0f), 47.0f);
        float wgt = ((t & 1) ? wx1 : wx0) * ((t >> 1) ? wy1 : wy0);
        tap[n][t] = yi * kWf + xi;
        tw[n][t] = inb ? wgt : 0.0f;
      }
      vmask |= (1 << n);
    }
  }
  const float inv_n = 1.0f / 6.0f;
#pragma unroll 4
  for (int k = 0; k < kCChunk; ++k) {
    const int c = c0 + k;
    float acc = 0.0f;
#pragma unroll
    for (int n = 0; n < kN; ++n) {
      if (vmask & (1 << n)) {
        const float* f = feats + ((size_t)(b * kN + n) * kC + c) * kHW;
        acc += f[tap[n][0]] * tw[n][0] + f[tap[n][1]] * tw[n][1] +
               f[tap[n][2]] * tw[n][2] + f[tap[n][3]] * tw[n][3];
      }
    }
    if (inrange) out[((size_t)b * kC + c) * kP + p] = acc * inv_n;
  }
}

}  // namespace

extern "C" void kernel_launch(void* const* d_in, const int* in_sizes, int n_in,
                              void* d_out, int out_size, void* d_ws,
                              size_t ws_size, hipStream_t stream) {
  const float* feats = (const float*)d_in[0];
  const float* intr = (const float*)d_in[1];
  const float* c2c = (const float*)d_in[2];
  float* out = (float*)d_out;

  if (ws_size >= kWsNeeded && d_ws != nullptr) {
    unsigned short* tf = (unsigned short*)d_ws;
    transpose_cvt_kernel<<<dim3(kHW / 32, kC / 64, kB * kN), 256, 0, stream>>>(
        feats, tf);
    gather_kernel<<<dim3(kNTiles, kB), 512, 0, stream>>>(
        (const unsigned char*)tf, intr, c2c, out);
  } else {
    dim3 grid((kP + 255) / 256, kB, kC / kCChunk);
    ipm_project_kernel<<<grid, dim3(256), 0, stream>>>(feats, intr, c2c, out);
  }
}